// Round 4
// baseline (728.890 us; speedup 1.0000x reference)
//
#include <hip/hip_runtime.h>

using short8 = __attribute__((ext_vector_type(8))) short;
using bf16x8 = __attribute__((ext_vector_type(8))) __bf16;
using f32x4  = __attribute__((ext_vector_type(4))) float;

__device__ __forceinline__ void gload_lds16(const void* g, void* l) {
  __builtin_amdgcn_global_load_lds(
      (const __attribute__((address_space(1))) void*)g,
      (__attribute__((address_space(3))) void*)l, 16, 0, 0);
}

// ---------------- prepass: decode/convert ----------------

__device__ __forceinline__ float dec_e4m3(int b) {
  int e = (b >> 3) & 15;
  int m = b & 7;
  if (e == 15 && m == 7) m = 6;  // NaN pattern -> 448 per reference
  float v;
  if (e) v = (1.0f + (float)m * 0.125f) * __uint_as_float((unsigned)(e + 120) << 23);
  else   v = (float)m * 0.001953125f;  // m * 2^-9
  return (b & 0x80) ? -v : v;
}

__global__ void dec_w_kernel(const int* __restrict__ wq,
                             unsigned short* __restrict__ wb, int n8) {
  int i = blockIdx.x * blockDim.x + threadIdx.x;
  if (i >= n8) return;
  const int4* p = (const int4*)wq + (size_t)i * 2;
  int4 a = p[0], b4 = p[1];
  int bv[8] = {a.x, a.y, a.z, a.w, b4.x, b4.y, b4.z, b4.w};
  short8 r;
#pragma unroll
  for (int j = 0; j < 8; ++j) {
    float f = dec_e4m3(bv[j]);
    r[j] = (short)(__float_as_uint(f) >> 16);  // exact (<=3 mantissa bits)
  }
  *(short8*)(wb + (size_t)i * 8) = r;
}

__global__ void cvt_x_kernel(const float* __restrict__ x,
                             unsigned short* __restrict__ xb, int n8) {
  int i = blockIdx.x * blockDim.x + threadIdx.x;
  if (i >= n8) return;
  const float4* p = (const float4*)x + (size_t)i * 2;
  float4 a = p[0], b4 = p[1];
  float v[8] = {a.x, a.y, a.z, a.w, b4.x, b4.y, b4.z, b4.w};
  short8 r;
#pragma unroll
  for (int j = 0; j < 8; ++j) {
    unsigned u = __float_as_uint(v[j]);
    u += 0x7FFFu + ((u >> 16) & 1u);  // RNE
    r[j] = (short)(u >> 16);
  }
  *(short8*)(xb + (size_t)i * 8) = r;
}

// ---------------- 256x256 GEMM: 16x16x32 MFMA + cross-phase prefetch ------
// C[t,o] = scale[o] * sum_k A[t,k]*B[o,k] + bias[o]
// A: [T][K] bf16, B: [N][K] bf16 (row-major, B^T GEMM). 512 thr = 8 waves
// (2M x 4N), per-wave C 128x64 = acc[8][4] 16x16 f32x4 frags.
// LDS 128KB: buf0 @0 (A 32K, B 32K), buf1 @65536. XOR swizzle
// byte ^= ((row&7)<<4) via pre-swizzled global source; reads use same XOR
// (R2: verified 0 bank conflicts with the 16-row fragment groups).
// Schedule: 1 barrier/phase; MFMA on regs prefetched last phase; stage
// issued right after MFMA; counted vmcnt BEFORE the barrier that precedes
// the consuming prefetch (cross-wave guarantee). Hazards audited R3/R4.

#define NOPV ((void)0)
#define VM8 asm volatile("s_waitcnt vmcnt(8)" ::: "memory")
#define VM4 asm volatile("s_waitcnt vmcnt(4)" ::: "memory")
#define VM2 asm volatile("s_waitcnt vmcnt(2)" ::: "memory")
#define VM0 asm volatile("s_waitcnt vmcnt(0)" ::: "memory")

#define STAGE_A(LOFF, KT, J) do { \
    const char* _g = gAb + (size_t)(KT) * 128u; \
    gload_lds16(_g + (size_t)((J) * 64) * Kb, lds + (LOFF) + ((J) * 64) * 128 + tdA); \
    gload_lds16(_g + (size_t)(128 + (J) * 64) * Kb, lds + (LOFF) + (128 + (J) * 64) * 128 + tdA); \
  } while (0)

#define STAGE_B(LOFF, KT, J) do { \
    const char* _g = gBb + (size_t)(KT) * 128u; \
    gload_lds16(_g + (size_t)((J) * 32) * Kb, lds + (LOFF) + 32768 + ((J) * 32) * 128 + tdB); \
    gload_lds16(_g + (size_t)(128 + (J) * 32) * Kb, lds + (LOFF) + 32768 + (128 + (J) * 32) * 128 + tdB); \
  } while (0)

// read A-quadrant QM: 4 Mfrag x 2 ks = 8 x ds_read_b128
#define RD_A(DST, LOFF, QM) do { \
    _Pragma("unroll") \
    for (int mi = 0; mi < 4; ++mi) { \
      const char* _b = lds + (LOFF) + (size_t)(arow + (QM) * 64 + mi * 16) * 128; \
      (DST)[mi * 2 + 0] = *(const bf16x8*)(_b + fo0); \
      (DST)[mi * 2 + 1] = *(const bf16x8*)(_b + fo1); \
    } \
  } while (0)

// read B-half QN: 2 Nfrag x 2 ks = 4 x ds_read_b128
#define RD_B(DST, LOFF, QN) do { \
    _Pragma("unroll") \
    for (int ni = 0; ni < 2; ++ni) { \
      const char* _b = lds + (LOFF) + 32768 + (size_t)(brow + ((QN) * 2 + ni) * 16) * 128; \
      (DST)[ni * 2 + 0] = *(const bf16x8*)(_b + fo0); \
      (DST)[ni * 2 + 1] = *(const bf16x8*)(_b + fo1); \
    } \
  } while (0)

// phase: MFMA on prefetched regs; stage; prefetch next; counted vm; barrier
#define PHASE(AB, BB, QM, QN, PFBLK, STBLK, VMBLK) do { \
    asm volatile("s_waitcnt lgkmcnt(0)" ::: "memory"); \
    __builtin_amdgcn_sched_barrier(0); \
    __builtin_amdgcn_s_setprio(1); \
    _Pragma("unroll") \
    for (int mi = 0; mi < 4; ++mi) \
      _Pragma("unroll") \
      for (int ni = 0; ni < 2; ++ni) \
        _Pragma("unroll") \
        for (int ks = 0; ks < 2; ++ks) \
          acc[(QM) * 4 + mi][(QN) * 2 + ni] = __builtin_amdgcn_mfma_f32_16x16x32_bf16( \
              (AB)[mi * 2 + ks], (BB)[ni * 2 + ks], acc[(QM) * 4 + mi][(QN) * 2 + ni], 0, 0, 0); \
    __builtin_amdgcn_s_setprio(0); \
    STBLK; \
    PFBLK; \
    VMBLK; \
    __builtin_amdgcn_s_barrier(); \
  } while (0)

__global__ __launch_bounds__(512, 2) void gemm256_kernel(
    const unsigned short* __restrict__ A, const unsigned short* __restrict__ B,
    const float* __restrict__ scale, const float* __restrict__ bias,
    float* __restrict__ out, int T, int K, int N) {
  extern __shared__ char lds[];
  const int L0 = 0, L1 = 65536;

  const int nbn = N >> 8;
  const int nwg = (T >> 8) * nbn;
  const int q = nwg >> 3, r = nwg & 7;
  const int xcd = blockIdx.x & 7, off = blockIdx.x >> 3;
  const int swz = (xcd < r ? xcd * (q + 1) : r * (q + 1) + (xcd - r) * q) + off;
  const int bm = (swz / nbn) << 8;
  const int bn = (swz % nbn) << 8;

  const int tid = threadIdx.x;
  const int wave = tid >> 6, lane = tid & 63;
  const int wm = wave >> 2, wn = wave & 3;
  const int nt = K >> 6;           // K-tiles (BK=64); requires nt even >= 4
  const size_t Kb = (size_t)K * 2;

  // staging: pre-swizzled global source, linear LDS dest (verified R2)
  const int trow = tid >> 3;
  const int gcol = ((tid & 7) * 16) ^ (((tid >> 3) & 7) << 4);
  const int bmap = ((tid & 256) ? 64 : 0) + ((tid >> 6) & 3) * 8 + ((tid >> 3) & 7);
  const char* gAb = (const char*)A + (size_t)(bm + trow) * Kb + gcol;
  const char* gBb = (const char*)B + (size_t)(bn + bmap) * Kb + gcol;
  const int tdA = tid * 16;
  const int tdB = bmap * 128 + (tid & 7) * 16;

  // fragment read offsets (R2, 0-conflict): row = .. + (lane&15)
  const int g16 = lane >> 4, l8 = lane & 7;
  const int fo0 = ((g16 ^ l8) << 4);
  const int fo1 = fo0 ^ 64;
  const int arow = wm * 128 + (lane & 15);
  const int brow = wn * 64 + (lane & 15);

  f32x4 acc[8][4] = {};
  bf16x8 aL[8], aH[8], b0[4], b1[4];

  // prologue: tile0 {Ah0,Bh0,Bh1,Ah1}, tile1 {Ah0,Bh0,Bh1} (14 loads);
  // VM8 leaves {Ah1(t0), Ah0(t1), Bh0(t1), Bh1(t1)} outstanding
  STAGE_A(L0, 0, 0);
  STAGE_B(L0, 0, 0);
  STAGE_B(L0, 0, 1);
  STAGE_A(L0, 0, 1);
  STAGE_A(L1, 1, 0);
  STAGE_B(L1, 1, 0);
  STAGE_B(L1, 1, 1);
  VM8;
  __builtin_amdgcn_s_barrier();
  RD_A(aL, L0, 0);
  RD_B(b0, L0, 0);

  int t = 0;
  for (; t + 3 < nt; t += 2) {
    // tile t (buf0; lo B bank = b0, hi = b1)
    PHASE(aL, b0, 0, 0, RD_B(b1, L0, 1), STAGE_A(L1, t + 1, 1), VM8);
    PHASE(aL, b1, 0, 1, RD_A(aH, L0, 1), STAGE_A(L0, t + 2, 0), NOPV);
    PHASE(aH, b1, 1, 1, NOPV,            STAGE_B(L0, t + 2, 0), VM8);
    PHASE(aH, b0, 1, 0, { RD_A(aL, L1, 0); RD_B(b1, L1, 0); },
                         STAGE_B(L0, t + 2, 1), VM8);
    // tile t+1 (buf1; lo B bank = b1, hi = b0)
    PHASE(aL, b1, 0, 0, RD_B(b0, L1, 1), STAGE_A(L0, t + 2, 1), VM8);
    PHASE(aL, b0, 0, 1, RD_A(aH, L1, 1), STAGE_A(L1, t + 3, 0), NOPV);
    PHASE(aH, b0, 1, 1, NOPV,            STAGE_B(L1, t + 3, 0), VM8);
    PHASE(aH, b1, 1, 0, { RD_A(aL, L0, 0); RD_B(b0, L0, 0); },
                         STAGE_B(L1, t + 3, 1), VM8);
  }
  // tail: tiles nt-2 (buf0), nt-1 (buf1); entry outstanding:
  // {Ah1(nt-2), Ah0(nt-1), Bh0(nt-1), Bh1(nt-1)} = 8
  PHASE(aL, b0, 0, 0, RD_B(b1, L0, 1), STAGE_A(L1, t + 1, 1), VM8);
  PHASE(aL, b1, 0, 1, RD_A(aH, L0, 1), NOPV, NOPV);
  PHASE(aH, b1, 1, 1, NOPV,            NOPV, VM4);
  PHASE(aH, b0, 1, 0, { RD_A(aL, L1, 0); RD_B(b1, L1, 0); }, NOPV, VM2);
  PHASE(aL, b1, 0, 0, RD_B(b0, L1, 1), NOPV, VM0);
  PHASE(aL, b0, 0, 1, RD_A(aH, L1, 1), NOPV, NOPV);
  PHASE(aH, b0, 1, 1, NOPV,            NOPV, NOPV);
  PHASE(aH, b1, 1, 0, NOPV,            NOPV, NOPV);

  // epilogue: 16x16 C/D layout: col=lane&15, row=(lane>>4)*4+reg
  const int ccol = bn + wn * 64 + (lane & 15);
  const int crow = bm + wm * 128 + ((lane >> 4) << 2);
#pragma unroll
  for (int ni = 0; ni < 4; ++ni) {
    const int o = ccol + ni * 16;
    const float sc = scale[o], bi = bias[o];
#pragma unroll
    for (int mi = 0; mi < 8; ++mi) {
#pragma unroll
      for (int rr = 0; rr < 4; ++rr) {
        out[(size_t)(crow + mi * 16 + rr) * N + o] = acc[mi][ni][rr] * sc + bi;
      }
    }
  }
}

// ---------------- m97 128x128 fallback ----------------

#define BM 128
#define BN 128
#define BK 64

__global__ __launch_bounds__(256) void gemm_bf16_kernel(
    const unsigned short* __restrict__ A, const unsigned short* __restrict__ B,
    const float* __restrict__ scale, const float* __restrict__ bias,
    float* __restrict__ out, int T, int K, int N) {
  __shared__ __align__(16) unsigned short lsA[BM * BK];
  __shared__ __align__(16) unsigned short lsB[BN * BK];

  const int nbn = N / BN;
  const int nwg = (T / BM) * nbn;
  const int q = nwg >> 3, r = nwg & 7;
  const int xcd = blockIdx.x & 7, off = blockIdx.x >> 3;
  const int swz = (xcd < r ? xcd * (q + 1) : r * (q + 1) + (xcd - r) * q) + off;
  const int bm = (swz / nbn) * BM;
  const int bn = (swz % nbn) * BN;

  const int tid = threadIdx.x;
  const int wave = tid >> 6, lane = tid & 63;
  const int wm = (wave >> 1) * 64, wn = (wave & 1) * 64;

  f32x4 acc[4][4] = {};

  const int srow = (wave << 3) + (lane >> 3);
  const int scolb = (lane & 7) * 16;
  const size_t Kb = (size_t)K * 2;
  const char* gA = (const char*)A + (size_t)bm * Kb + scolb;
  const char* gB = (const char*)B + (size_t)bn * Kb + scolb;
  char* laddrA = (char*)lsA + wave * 1024;
  char* laddrB = (char*)lsB + wave * 1024;

  for (int k0 = 0; k0 < K; k0 += BK) {
    const char* pa = gA + (size_t)k0 * 2;
    const char* pb = gB + (size_t)k0 * 2;
#pragma unroll
    for (int s = 0; s < 4; ++s) {
      int row = s * 32 + srow;
      gload_lds16(pa + (size_t)row * Kb, laddrA + s * 4096);
      gload_lds16(pb + (size_t)row * Kb, laddrB + s * 4096);
    }
    __syncthreads();

    const int arow2 = wm + (lane & 15);
    const int brow2 = wn + (lane & 15);
#pragma unroll
    for (int kk = 0; kk < BK; kk += 32) {
      const int kcol = kk + ((lane >> 4) << 3);
      bf16x8 af[4], bfr[4];
#pragma unroll
      for (int i = 0; i < 4; ++i)
        af[i] = *(const bf16x8*)(lsA + (size_t)(arow2 + i * 16) * BK + kcol);
#pragma unroll
      for (int i = 0; i < 4; ++i)
        bfr[i] = *(const bf16x8*)(lsB + (size_t)(brow2 + i * 16) * BK + kcol);
#pragma unroll
      for (int mi = 0; mi < 4; ++mi)
#pragma unroll
        for (int ni = 0; ni < 4; ++ni)
          acc[mi][ni] = __builtin_amdgcn_mfma_f32_16x16x32_bf16(
              af[mi], bfr[ni], acc[mi][ni], 0, 0, 0);
    }
    __syncthreads();
  }

  const int ccol = bn + wn + (lane & 15);
  const int crow0 = bm + wm + ((lane >> 4) << 2);
#pragma unroll
  for (int ni = 0; ni < 4; ++ni) {
    const int o = ccol + ni * 16;
    const float sc = scale[o], bi = bias[o];
#pragma unroll
    for (int mi = 0; mi < 4; ++mi) {
#pragma unroll
      for (int rr = 0; rr < 4; ++rr) {
        const int t2 = crow0 + mi * 16 + rr;
        out[(size_t)t2 * N + o] = acc[mi][ni][rr] * sc + bi;
      }
    }
  }
}

// ---------------- naive fallback ----------------

__global__ void naive_kernel(const float* __restrict__ X, const int* __restrict__ Wq,
                             const float* __restrict__ sc, const float* __restrict__ bs,
                             float* __restrict__ out, int T, int K, int N) {
  __shared__ float xt[16][16];
  __shared__ float wt[16][17];
  const int tx = threadIdx.x & 15, ty = threadIdx.x >> 4;
  const int t = blockIdx.y * 16 + ty, o = blockIdx.x * 16 + tx;
  float acc = 0.f;
  for (int k0 = 0; k0 < K; k0 += 16) {
    xt[ty][tx] = X[(size_t)t * K + k0 + tx];
    wt[ty][tx] = dec_e4m3(Wq[(size_t)(blockIdx.x * 16 + ty) * K + k0 + tx]);
    __syncthreads();
#pragma unroll
    for (int kk = 0; kk < 16; ++kk) acc += xt[ty][kk] * wt[tx][kk];
    __syncthreads();
  }
  out[(size_t)t * N + o] = acc * sc[o] + bs[o];
}

extern "C" void kernel_launch(void* const* d_in, const int* in_sizes, int n_in,
                              void* d_out, int out_size, void* d_ws, size_t ws_size,
                              hipStream_t stream) {
  const float* x  = (const float*)d_in[0];
  const int*   wq = (const int*)d_in[1];
  const float* sc = (const float*)d_in[2];
  const float* bi = (const float*)d_in[3];
  float* out = (float*)d_out;

  const int DOUT = in_sizes[2];
  const int DIN  = in_sizes[1] / DOUT;
  const int T    = in_sizes[0] / DIN;

  const size_t need = ((size_t)T * DIN + (size_t)DOUT * DIN) * 2;
  const bool ok256 = (T % 256 == 0) && (DOUT % 256 == 0) && (DIN % 256 == 0);
  const bool ok128 = (T % BM == 0) && (DOUT % BN == 0) && (DIN % BK == 0);

  if (ws_size >= need && (ok256 || ok128)) {
    unsigned short* xb = (unsigned short*)d_ws;
    unsigned short* wb = xb + (size_t)T * DIN;
    const int nx8 = (int)((size_t)T * DIN / 8);
    const int nw8 = (int)((size_t)DOUT * DIN / 8);
    cvt_x_kernel<<<(nx8 + 255) / 256, 256, 0, stream>>>(x, xb, nx8);
    dec_w_kernel<<<(nw8 + 255) / 256, 256, 0, stream>>>(wq, wb, nw8);
    if (ok256) {
      dim3 grid((T >> 8) * (DOUT >> 8));
      gemm256_kernel<<<grid, 512, 131072, stream>>>(xb, wb, sc, bi, out, T, DIN, DOUT);
    } else {
      dim3 grid((T / BM) * (DOUT / BN));
      gemm_bf16_kernel<<<grid, 256, 0, stream>>>(xb, wb, sc, bi, out, T, DIN, DOUT);
    }
  } else {
    dim3 g(DOUT / 16, T / 16);
    naive_kernel<<<g, 256, 0, stream>>>(x, wq, sc, bi, out, T, DIN, DOUT);
  }
}

// Round 5
// 545.431 us; speedup vs baseline: 1.3364x; 1.3364x over previous
//
#include <hip/hip_runtime.h>

using short8 = __attribute__((ext_vector_type(8))) short;
using bf16x8 = __attribute__((ext_vector_type(8))) __bf16;
using f32x4  = __attribute__((ext_vector_type(4))) float;

__device__ __forceinline__ void gload_lds16(const void* g, void* l) {
  __builtin_amdgcn_global_load_lds(
      (const __attribute__((address_space(1))) void*)g,
      (__attribute__((address_space(3))) void*)l, 16, 0, 0);
}

// ---------------- prepass: decode/convert ----------------

__device__ __forceinline__ float dec_e4m3(int b) {
  int e = (b >> 3) & 15;
  int m = b & 7;
  if (e == 15 && m == 7) m = 6;  // NaN pattern -> 448 per reference
  float v;
  if (e) v = (1.0f + (float)m * 0.125f) * __uint_as_float((unsigned)(e + 120) << 23);
  else   v = (float)m * 0.001953125f;  // m * 2^-9
  return (b & 0x80) ? -v : v;
}

__global__ void dec_w_kernel(const int* __restrict__ wq,
                             unsigned short* __restrict__ wb, int n8) {
  int i = blockIdx.x * blockDim.x + threadIdx.x;
  if (i >= n8) return;
  const int4* p = (const int4*)wq + (size_t)i * 2;
  int4 a = p[0], b4 = p[1];
  int bv[8] = {a.x, a.y, a.z, a.w, b4.x, b4.y, b4.z, b4.w};
  short8 r;
#pragma unroll
  for (int j = 0; j < 8; ++j) {
    float f = dec_e4m3(bv[j]);
    r[j] = (short)(__float_as_uint(f) >> 16);  // exact (<=3 mantissa bits)
  }
  *(short8*)(wb + (size_t)i * 8) = r;
}

__global__ void cvt_x_kernel(const float* __restrict__ x,
                             unsigned short* __restrict__ xb, int n8) {
  int i = blockIdx.x * blockDim.x + threadIdx.x;
  if (i >= n8) return;
  const float4* p = (const float4*)x + (size_t)i * 2;
  float4 a = p[0], b4 = p[1];
  float v[8] = {a.x, a.y, a.z, a.w, b4.x, b4.y, b4.z, b4.w};
  short8 r;
#pragma unroll
  for (int j = 0; j < 8; ++j) {
    unsigned u = __float_as_uint(v[j]);
    u += 0x7FFFu + ((u >> 16) & 1u);  // RNE
    r[j] = (short)(u >> 16);
  }
  *(short8*)(xb + (size_t)i * 8) = r;
}

// ---------------- 256x256 8-phase GEMM (R2-proven m201 template) ----------
// C[t,o] = scale[o] * sum_k A[t,k]*B[o,k] + bias[o]
// A: [T][K] bf16, B: [N][K] bf16 (both row-major, B^T GEMM).
// 512 thr = 8 waves (2M x 4N), per-wave C block 128x64.
// LDS: 2 x (A 32KB + B 32KB) = 128KB dynamic.
// Swizzle: LDS[row][c ^ ((row&7)<<4)]; staged via pre-swizzled GLOBAL source
// (gload_lds dest stays linear), read with same XOR. 0 bank conflicts (R2).
// R5 delta vs R2: epilogue uses nontemporal stores (don't allocate the
// 256MB streaming output in L2/L3 -> stop thrashing the cached B panel).

#define NOPV ((void)0)
#define VM6 asm volatile("s_waitcnt vmcnt(6)" ::: "memory")
#define VM0 asm volatile("s_waitcnt vmcnt(0)" ::: "memory")

#define STAGE_A(LBUF, KT, J) do { \
    const char* _g = gAb + (size_t)(KT) * 128u; \
    gload_lds16(_g + (size_t)((J) * 64) * Kb, (LBUF) + ((J) * 64) * 128 + tdA); \
    gload_lds16(_g + (size_t)(128 + (J) * 64) * Kb, (LBUF) + (128 + (J) * 64) * 128 + tdA); \
  } while (0)

#define STAGE_B(LBUF, KT, J) do { \
    const char* _g = gBb + (size_t)(KT) * 128u; \
    gload_lds16(_g + (size_t)((J) * 32) * Kb, (LBUF) + ((J) * 32) * 128 + tdB); \
    gload_lds16(_g + (size_t)(128 + (J) * 32) * Kb, (LBUF) + (128 + (J) * 32) * 128 + tdB); \
  } while (0)

#define PHASE(QM, QN, DOA, DOB, STAGE, LGK8, VM) { \
    if (DOA) { \
      _Pragma("unroll") \
      for (int mi = 0; mi < 4; ++mi) { \
        const char* _b = lA + (size_t)(arow + (QM) * 64 + mi * 16) * 128; \
        a[mi][0] = *(const bf16x8*)(_b + fo0); \
        a[mi][1] = *(const bf16x8*)(_b + fo1); \
      } \
    } \
    if (DOB) { \
      _Pragma("unroll") \
      for (int ni = 0; ni < 2; ++ni) { \
        const char* _b = lB + (size_t)(brow + ((QN) * 2 + ni) * 16) * 128; \
        b[(QN) * 2 + ni][0] = *(const bf16x8*)(_b + fo0); \
        b[(QN) * 2 + ni][1] = *(const bf16x8*)(_b + fo1); \
      } \
    } \
    STAGE; \
    if (LGK8) asm volatile("s_waitcnt lgkmcnt(8)" ::: "memory"); \
    __builtin_amdgcn_s_barrier(); \
    asm volatile("s_waitcnt lgkmcnt(0)" ::: "memory"); \
    __builtin_amdgcn_sched_barrier(0); \
    __builtin_amdgcn_s_setprio(1); \
    _Pragma("unroll") \
    for (int mi = 0; mi < 4; ++mi) \
      _Pragma("unroll") \
      for (int ni = 0; ni < 2; ++ni) \
        _Pragma("unroll") \
        for (int ks = 0; ks < 2; ++ks) \
          acc[(QM) * 4 + mi][(QN) * 2 + ni] = __builtin_amdgcn_mfma_f32_16x16x32_bf16( \
              a[mi][ks], b[(QN) * 2 + ni][ks], acc[(QM) * 4 + mi][(QN) * 2 + ni], 0, 0, 0); \
    __builtin_amdgcn_s_setprio(0); \
    VM; \
    __builtin_amdgcn_s_barrier(); \
  }

__global__ __launch_bounds__(512, 2) void gemm256_kernel(
    const unsigned short* __restrict__ A, const unsigned short* __restrict__ B,
    const float* __restrict__ scale, const float* __restrict__ bias,
    float* __restrict__ out, int T, int K, int N) {
  extern __shared__ char lds[];
  char* const lA0 = lds;
  char* const lB0 = lds + 32768;
  char* const lA1 = lds + 65536;
  char* const lB1 = lds + 98304;

  const int nbn = N >> 8;
  const int nwg = (T >> 8) * nbn;
  const int q = nwg >> 3, r = nwg & 7;
  const int xcd = blockIdx.x & 7, off = blockIdx.x >> 3;
  const int swz = (xcd < r ? xcd * (q + 1) : r * (q + 1) + (xcd - r) * q) + off;
  const int bm = (swz / nbn) << 8;
  const int bn = (swz % nbn) << 8;

  const int tid = threadIdx.x;
  const int wave = tid >> 6, lane = tid & 63;
  const int wm = wave >> 2, wn = wave & 3;
  const int nt = K >> 6;           // K-tiles (BK=64); requires nt even >= 4
  const size_t Kb = (size_t)K * 2; // row stride bytes

  // staging addresses (pre-swizzled global source, linear LDS dest)
  const int trow = tid >> 3;                       // 0..63
  const int gcol = ((tid & 7) * 16) ^ (((tid >> 3) & 7) << 4);
  const int bmap = ((tid & 256) ? 64 : 0) + ((tid >> 6) & 3) * 8 + ((tid >> 3) & 7);
  const char* gAb = (const char*)A + (size_t)(bm + trow) * Kb + gcol;
  const char* gBb = (const char*)B + (size_t)(bn + bmap) * Kb + gcol;
  const int tdA = tid * 16;
  const int tdB = bmap * 128 + (tid & 7) * 16;

  // ds_read fragment addressing (same XOR swizzle)
  const int g16 = lane >> 4, l8 = lane & 7;
  const int fo0 = ((g16 ^ l8) << 4);
  const int fo1 = fo0 ^ 64;
  const int arow = wm * 128 + (lane & 15);
  const int brow = wn * 64 + (lane & 15);

  f32x4 acc[8][4] = {};
  bf16x8 a[4][2], b[4][2];
  const char *lA, *lB;

  // prologue: tile0 {A0,B0,B1,A1}; tile1 {A0,B0,B1}; vmcnt(6) -> tile0 ready
  STAGE_A(lA0, 0, 0);
  STAGE_B(lB0, 0, 0);
  STAGE_B(lB0, 0, 1);
  STAGE_A(lA0, 0, 1);
  STAGE_A(lA1, 1, 0);
  STAGE_B(lB1, 1, 0);
  STAGE_B(lB1, 1, 1);
  VM6;
  __builtin_amdgcn_s_barrier();

  int t = 0;
  for (; t + 3 < nt; t += 2) {
    // tile t (buf0): stages -> t+1 A-h1 (buf1), then t+2 A-h0/B-h0/B-h1 (buf0)
    lA = lA0; lB = lB0;
    PHASE(0, 0, 1, 1, STAGE_A(lA1, t + 1, 1), 1, NOPV)
    PHASE(0, 1, 0, 1, STAGE_A(lA0, t + 2, 0), 0, NOPV)
    PHASE(1, 1, 1, 0, STAGE_B(lB0, t + 2, 0), 0, NOPV)
    PHASE(1, 0, 0, 0, STAGE_B(lB0, t + 2, 1), 0, VM6)
    // tile t+1 (buf1): stages -> t+2 A-h1 (buf0), then t+3 ... (buf1)
    lA = lA1; lB = lB1;
    PHASE(0, 0, 1, 1, STAGE_A(lA0, t + 2, 1), 1, NOPV)
    PHASE(0, 1, 0, 1, STAGE_A(lA1, t + 3, 0), 0, NOPV)
    PHASE(1, 1, 1, 0, STAGE_B(lB1, t + 3, 0), 0, NOPV)
    PHASE(1, 0, 0, 0, STAGE_B(lB1, t + 3, 1), 0, VM6)
  }
  // tail: tiles nt-2 (buf0), nt-1 (buf1)
  lA = lA0; lB = lB0;
  PHASE(0, 0, 1, 1, STAGE_A(lA1, t + 1, 1), 1, NOPV)
  PHASE(0, 1, 0, 1, NOPV, 0, NOPV)
  PHASE(1, 1, 1, 0, NOPV, 0, NOPV)
  PHASE(1, 0, 0, 0, NOPV, 0, VM0)
  lA = lA1; lB = lB1;
  PHASE(0, 0, 1, 1, NOPV, 1, NOPV)
  PHASE(0, 1, 0, 1, NOPV, 0, NOPV)
  PHASE(1, 1, 1, 0, NOPV, 0, NOPV)
  PHASE(1, 0, 0, 0, NOPV, 0, NOPV)

  // epilogue: C/D layout col=lane&15, row=(lane>>4)*4+reg
  // nontemporal: streaming 256MB output must not evict the L3-cached B panel
  const int ccol = bn + wn * 64 + (lane & 15);
  const int crow = bm + wm * 128 + ((lane >> 4) << 2);
#pragma unroll
  for (int ni = 0; ni < 4; ++ni) {
    const int o = ccol + ni * 16;
    const float sc = scale[o], bi = bias[o];
#pragma unroll
    for (int mi = 0; mi < 8; ++mi) {
#pragma unroll
      for (int rr = 0; rr < 4; ++rr) {
        __builtin_nontemporal_store(acc[mi][ni][rr] * sc + bi,
                                    &out[(size_t)(crow + mi * 16 + rr) * N + o]);
      }
    }
  }
}

// ---------------- m97 128x128 fallback ----------------

#define BM 128
#define BN 128
#define BK 64

__global__ __launch_bounds__(256) void gemm_bf16_kernel(
    const unsigned short* __restrict__ A, const unsigned short* __restrict__ B,
    const float* __restrict__ scale, const float* __restrict__ bias,
    float* __restrict__ out, int T, int K, int N) {
  __shared__ __align__(16) unsigned short lsA[BM * BK];
  __shared__ __align__(16) unsigned short lsB[BN * BK];

  const int nbn = N / BN;
  const int nwg = (T / BM) * nbn;
  const int q = nwg >> 3, r = nwg & 7;
  const int xcd = blockIdx.x & 7, off = blockIdx.x >> 3;
  const int swz = (xcd < r ? xcd * (q + 1) : r * (q + 1) + (xcd - r) * q) + off;
  const int bm = (swz / nbn) * BM;
  const int bn = (swz % nbn) * BN;

  const int tid = threadIdx.x;
  const int wave = tid >> 6, lane = tid & 63;
  const int wm = (wave >> 1) * 64, wn = (wave & 1) * 64;

  f32x4 acc[4][4] = {};

  const int srow = (wave << 3) + (lane >> 3);
  const int scolb = (lane & 7) * 16;
  const size_t Kb = (size_t)K * 2;
  const char* gA = (const char*)A + (size_t)bm * Kb + scolb;
  const char* gB = (const char*)B + (size_t)bn * Kb + scolb;
  char* laddrA = (char*)lsA + wave * 1024;
  char* laddrB = (char*)lsB + wave * 1024;

  for (int k0 = 0; k0 < K; k0 += BK) {
    const char* pa = gA + (size_t)k0 * 2;
    const char* pb = gB + (size_t)k0 * 2;
#pragma unroll
    for (int s = 0; s < 4; ++s) {
      int row = s * 32 + srow;
      gload_lds16(pa + (size_t)row * Kb, laddrA + s * 4096);
      gload_lds16(pb + (size_t)row * Kb, laddrB + s * 4096);
    }
    __syncthreads();

    const int arow2 = wm + (lane & 15);
    const int brow2 = wn + (lane & 15);
#pragma unroll
    for (int kk = 0; kk < BK; kk += 32) {
      const int kcol = kk + ((lane >> 4) << 3);
      bf16x8 af[4], bfr[4];
#pragma unroll
      for (int i = 0; i < 4; ++i)
        af[i] = *(const bf16x8*)(lsA + (size_t)(arow2 + i * 16) * BK + kcol);
#pragma unroll
      for (int i = 0; i < 4; ++i)
        bfr[i] = *(const bf16x8*)(lsB + (size_t)(brow2 + i * 16) * BK + kcol);
#pragma unroll
      for (int mi = 0; mi < 4; ++mi)
#pragma unroll
        for (int ni = 0; ni < 4; ++ni)
          acc[mi][ni] = __builtin_amdgcn_mfma_f32_16x16x32_bf16(
              af[mi], bfr[ni], acc[mi][ni], 0, 0, 0);
    }
    __syncthreads();
  }

  const int ccol = bn + wn + (lane & 15);
  const int crow0 = bm + wm + ((lane >> 4) << 2);
#pragma unroll
  for (int ni = 0; ni < 4; ++ni) {
    const int o = ccol + ni * 16;
    const float sc = scale[o], bi = bias[o];
#pragma unroll
    for (int mi = 0; mi < 4; ++mi) {
#pragma unroll
      for (int rr = 0; rr < 4; ++rr) {
        const int t2 = crow0 + mi * 16 + rr;
        out[(size_t)t2 * N + o] = acc[mi][ni][rr] * sc + bi;
      }
    }
  }
}

// ---------------- naive fallback ----------------

__global__ void naive_kernel(const float* __restrict__ X, const int* __restrict__ Wq,
                             const float* __restrict__ sc, const float* __restrict__ bs,
                             float* __restrict__ out, int T, int K, int N) {
  __shared__ float xt[16][16];
  __shared__ float wt[16][17];
  const int tx = threadIdx.x & 15, ty = threadIdx.x >> 4;
  const int t = blockIdx.y * 16 + ty, o = blockIdx.x * 16 + tx;
  float acc = 0.f;
  for (int k0 = 0; k0 < K; k0 += 16) {
    xt[ty][tx] = X[(size_t)t * K + k0 + tx];
    wt[ty][tx] = dec_e4m3(Wq[(size_t)(blockIdx.x * 16 + ty) * K + k0 + tx]);
    __syncthreads();
#pragma unroll
    for (int kk = 0; kk < 16; ++kk) acc += xt[ty][kk] * wt[tx][kk];
    __syncthreads();
  }
  out[(size_t)t * N + o] = acc * sc[o] + bs[o];
}

extern "C" void kernel_launch(void* const* d_in, const int* in_sizes, int n_in,
                              void* d_out, int out_size, void* d_ws, size_t ws_size,
                              hipStream_t stream) {
  const float* x  = (const float*)d_in[0];
  const int*   wq = (const int*)d_in[1];
  const float* sc = (const float*)d_in[2];
  const float* bi = (const float*)d_in[3];
  float* out = (float*)d_out;

  const int DOUT = in_sizes[2];
  const int DIN  = in_sizes[1] / DOUT;
  const int T    = in_sizes[0] / DIN;

  const size_t need = ((size_t)T * DIN + (size_t)DOUT * DIN) * 2;
  const bool ok256 = (T % 256 == 0) && (DOUT % 256 == 0) && (DIN % 256 == 0);
  const bool ok128 = (T % BM == 0) && (DOUT % BN == 0) && (DIN % BK == 0);

  if (ws_size >= need && (ok256 || ok128)) {
    unsigned short* xb = (unsigned short*)d_ws;
    unsigned short* wb = xb + (size_t)T * DIN;
    const int nx8 = (int)((size_t)T * DIN / 8);
    const int nw8 = (int)((size_t)DOUT * DIN / 8);
    cvt_x_kernel<<<(nx8 + 255) / 256, 256, 0, stream>>>(x, xb, nx8);
    dec_w_kernel<<<(nw8 + 255) / 256, 256, 0, stream>>>(wq, wb, nw8);
    if (ok256) {
      dim3 grid((T >> 8) * (DOUT >> 8));
      gemm256_kernel<<<grid, 512, 131072, stream>>>(xb, wb, sc, bi, out, T, DIN, DOUT);
    } else {
      dim3 grid((T / BM) * (DOUT / BN));
      gemm_bf16_kernel<<<grid, 256, 0, stream>>>(xb, wb, sc, bi, out, T, DIN, DOUT);
    }
  } else {
    dim3 g(DOUT / 16, T / 16);
    naive_kernel<<<g, 256, 0, stream>>>(x, wq, sc, bi, out, T, DIN, DOUT);
  }
}

// Round 6
// 517.264 us; speedup vs baseline: 1.4091x; 1.0545x over previous
//
#include <hip/hip_runtime.h>

using short8 = __attribute__((ext_vector_type(8))) short;
using bf16x8 = __attribute__((ext_vector_type(8))) __bf16;
using f32x4  = __attribute__((ext_vector_type(4))) float;

__device__ __forceinline__ void gload_lds16(const void* g, void* l) {
  __builtin_amdgcn_global_load_lds(
      (const __attribute__((address_space(1))) void*)g,
      (__attribute__((address_space(3))) void*)l, 16, 0, 0);
}

// ---------------- prepass: decode/convert ----------------

__device__ __forceinline__ float dec_e4m3(int b) {
  int e = (b >> 3) & 15;
  int m = b & 7;
  if (e == 15 && m == 7) m = 6;  // NaN pattern -> 448 per reference
  float v;
  if (e) v = (1.0f + (float)m * 0.125f) * __uint_as_float((unsigned)(e + 120) << 23);
  else   v = (float)m * 0.001953125f;  // m * 2^-9
  return (b & 0x80) ? -v : v;
}

__global__ void dec_w_kernel(const int* __restrict__ wq,
                             unsigned short* __restrict__ wb, int n8) {
  int i = blockIdx.x * blockDim.x + threadIdx.x;
  if (i >= n8) return;
  const int4* p = (const int4*)wq + (size_t)i * 2;
  int4 a = p[0], b4 = p[1];
  int bv[8] = {a.x, a.y, a.z, a.w, b4.x, b4.y, b4.z, b4.w};
  short8 r;
#pragma unroll
  for (int j = 0; j < 8; ++j) {
    float f = dec_e4m3(bv[j]);
    r[j] = (short)(__float_as_uint(f) >> 16);  // exact (<=3 mantissa bits)
  }
  *(short8*)(wb + (size_t)i * 8) = r;
}

__global__ void cvt_x_kernel(const float* __restrict__ x,
                             unsigned short* __restrict__ xb, int n8) {
  int i = blockIdx.x * blockDim.x + threadIdx.x;
  if (i >= n8) return;
  const float4* p = (const float4*)x + (size_t)i * 2;
  float4 a = p[0], b4 = p[1];
  float v[8] = {a.x, a.y, a.z, a.w, b4.x, b4.y, b4.z, b4.w};
  short8 r;
#pragma unroll
  for (int j = 0; j < 8; ++j) {
    unsigned u = __float_as_uint(v[j]);
    u += 0x7FFFu + ((u >> 16) & 1u);  // RNE
    r[j] = (short)(u >> 16);
  }
  *(short8*)(xb + (size_t)i * 8) = r;
}

// ---------------- 256x256 8-phase GEMM (R2-proven m201 template) ----------
// C[t,o] = scale[o] * sum_k A[t,k]*B[o,k] + bias[o]
// A: [T][K] bf16, B: [N][K] bf16 (both row-major, B^T GEMM).
// 512 thr = 8 waves (2M x 4N), per-wave C block 128x64.
// LDS: 2 x (A 32KB + B 32KB) = 128KB dynamic.
// Swizzle: LDS[row][c ^ ((row&7)<<4)]; staged via pre-swizzled GLOBAL source
// (gload_lds dest stays linear), read with same XOR. 0 bank conflicts (R2).
// R5: nontemporal epilogue stores (keep). R6: 2-D locality block mapping --
// each XCD owns a 4-wide bn supertile column for the whole dispatch so B
// stays L2/L3-hot instead of being re-streamed every bm round.

#define NOPV ((void)0)
#define VM6 asm volatile("s_waitcnt vmcnt(6)" ::: "memory")
#define VM0 asm volatile("s_waitcnt vmcnt(0)" ::: "memory")

#define STAGE_A(LBUF, KT, J) do { \
    const char* _g = gAb + (size_t)(KT) * 128u; \
    gload_lds16(_g + (size_t)((J) * 64) * Kb, (LBUF) + ((J) * 64) * 128 + tdA); \
    gload_lds16(_g + (size_t)(128 + (J) * 64) * Kb, (LBUF) + (128 + (J) * 64) * 128 + tdA); \
  } while (0)

#define STAGE_B(LBUF, KT, J) do { \
    const char* _g = gBb + (size_t)(KT) * 128u; \
    gload_lds16(_g + (size_t)((J) * 32) * Kb, (LBUF) + ((J) * 32) * 128 + tdB); \
    gload_lds16(_g + (size_t)(128 + (J) * 32) * Kb, (LBUF) + (128 + (J) * 32) * 128 + tdB); \
  } while (0)

#define PHASE(QM, QN, DOA, DOB, STAGE, LGK8, VM) { \
    if (DOA) { \
      _Pragma("unroll") \
      for (int mi = 0; mi < 4; ++mi) { \
        const char* _b = lA + (size_t)(arow + (QM) * 64 + mi * 16) * 128; \
        a[mi][0] = *(const bf16x8*)(_b + fo0); \
        a[mi][1] = *(const bf16x8*)(_b + fo1); \
      } \
    } \
    if (DOB) { \
      _Pragma("unroll") \
      for (int ni = 0; ni < 2; ++ni) { \
        const char* _b = lB + (size_t)(brow + ((QN) * 2 + ni) * 16) * 128; \
        b[(QN) * 2 + ni][0] = *(const bf16x8*)(_b + fo0); \
        b[(QN) * 2 + ni][1] = *(const bf16x8*)(_b + fo1); \
      } \
    } \
    STAGE; \
    if (LGK8) asm volatile("s_waitcnt lgkmcnt(8)" ::: "memory"); \
    __builtin_amdgcn_s_barrier(); \
    asm volatile("s_waitcnt lgkmcnt(0)" ::: "memory"); \
    __builtin_amdgcn_sched_barrier(0); \
    __builtin_amdgcn_s_setprio(1); \
    _Pragma("unroll") \
    for (int mi = 0; mi < 4; ++mi) \
      _Pragma("unroll") \
      for (int ni = 0; ni < 2; ++ni) \
        _Pragma("unroll") \
        for (int ks = 0; ks < 2; ++ks) \
          acc[(QM) * 4 + mi][(QN) * 2 + ni] = __builtin_amdgcn_mfma_f32_16x16x32_bf16( \
              a[mi][ks], b[(QN) * 2 + ni][ks], acc[(QM) * 4 + mi][(QN) * 2 + ni], 0, 0, 0); \
    __builtin_amdgcn_s_setprio(0); \
    VM; \
    __builtin_amdgcn_s_barrier(); \
  }

__global__ __launch_bounds__(512, 2) void gemm256_kernel(
    const unsigned short* __restrict__ A, const unsigned short* __restrict__ B,
    const float* __restrict__ scale, const float* __restrict__ bias,
    float* __restrict__ out, int T, int K, int N) {
  extern __shared__ char lds[];
  char* const lA0 = lds;
  char* const lB0 = lds + 32768;
  char* const lA1 = lds + 65536;
  char* const lB1 = lds + 98304;

  const int nbn = N >> 8;
  const int nbm = T >> 8;
  const int nwg = nbm * nbn;
  int bm, bn;
  if ((nbn & 31) == 0 && (nwg & 7) == 0) {
    // R6 locality mapping: XCD x owns bn supertile column(s) of width 4 for
    // the whole dispatch; walks bm within the column (bn fastest, stride 4).
    // Concurrent 32 blocks/XCD share 8 A-panels + 4 B-panels (~24 MB).
    const int xcd = blockIdx.x & 7, off = blockIdx.x >> 3;
    const int bpc = nbm << 2;                 // blocks per supertile column
    const int col = xcd * (nbn >> 5) + off / bpc;
    const int c   = off % bpc;
    bm = (c >> 2) << 8;
    bn = (col * 4 + (c & 3)) << 8;
  } else {
    // bijective m204 fallback
    const int q = nwg >> 3, r = nwg & 7;
    const int xcd = blockIdx.x & 7, off = blockIdx.x >> 3;
    const int swz = (xcd < r ? xcd * (q + 1) : r * (q + 1) + (xcd - r) * q) + off;
    bm = (swz / nbn) << 8;
    bn = (swz % nbn) << 8;
  }

  const int tid = threadIdx.x;
  const int wave = tid >> 6, lane = tid & 63;
  const int wm = wave >> 2, wn = wave & 3;
  const int nt = K >> 6;           // K-tiles (BK=64); requires nt even >= 4
  const size_t Kb = (size_t)K * 2; // row stride bytes

  // staging addresses (pre-swizzled global source, linear LDS dest)
  const int trow = tid >> 3;                       // 0..63
  const int gcol = ((tid & 7) * 16) ^ (((tid >> 3) & 7) << 4);
  const int bmap = ((tid & 256) ? 64 : 0) + ((tid >> 6) & 3) * 8 + ((tid >> 3) & 7);
  const char* gAb = (const char*)A + (size_t)(bm + trow) * Kb + gcol;
  const char* gBb = (const char*)B + (size_t)(bn + bmap) * Kb + gcol;
  const int tdA = tid * 16;
  const int tdB = bmap * 128 + (tid & 7) * 16;

  // ds_read fragment addressing (same XOR swizzle)
  const int g16 = lane >> 4, l8 = lane & 7;
  const int fo0 = ((g16 ^ l8) << 4);
  const int fo1 = fo0 ^ 64;
  const int arow = wm * 128 + (lane & 15);
  const int brow = wn * 64 + (lane & 15);

  f32x4 acc[8][4] = {};
  bf16x8 a[4][2], b[4][2];
  const char *lA, *lB;

  // prologue: tile0 {A0,B0,B1,A1}; tile1 {A0,B0,B1}; vmcnt(6) -> tile0 ready
  STAGE_A(lA0, 0, 0);
  STAGE_B(lB0, 0, 0);
  STAGE_B(lB0, 0, 1);
  STAGE_A(lA0, 0, 1);
  STAGE_A(lA1, 1, 0);
  STAGE_B(lB1, 1, 0);
  STAGE_B(lB1, 1, 1);
  VM6;
  __builtin_amdgcn_s_barrier();

  int t = 0;
  for (; t + 3 < nt; t += 2) {
    // tile t (buf0): stages -> t+1 A-h1 (buf1), then t+2 A-h0/B-h0/B-h1 (buf0)
    lA = lA0; lB = lB0;
    PHASE(0, 0, 1, 1, STAGE_A(lA1, t + 1, 1), 1, NOPV)
    PHASE(0, 1, 0, 1, STAGE_A(lA0, t + 2, 0), 0, NOPV)
    PHASE(1, 1, 1, 0, STAGE_B(lB0, t + 2, 0), 0, NOPV)
    PHASE(1, 0, 0, 0, STAGE_B(lB0, t + 2, 1), 0, VM6)
    // tile t+1 (buf1): stages -> t+2 A-h1 (buf0), then t+3 ... (buf1)
    lA = lA1; lB = lB1;
    PHASE(0, 0, 1, 1, STAGE_A(lA0, t + 2, 1), 1, NOPV)
    PHASE(0, 1, 0, 1, STAGE_A(lA1, t + 3, 0), 0, NOPV)
    PHASE(1, 1, 1, 0, STAGE_B(lB1, t + 3, 0), 0, NOPV)
    PHASE(1, 0, 0, 0, STAGE_B(lB1, t + 3, 1), 0, VM6)
  }
  // tail: tiles nt-2 (buf0), nt-1 (buf1)
  lA = lA0; lB = lB0;
  PHASE(0, 0, 1, 1, STAGE_A(lA1, t + 1, 1), 1, NOPV)
  PHASE(0, 1, 0, 1, NOPV, 0, NOPV)
  PHASE(1, 1, 1, 0, NOPV, 0, NOPV)
  PHASE(1, 0, 0, 0, NOPV, 0, VM0)
  lA = lA1; lB = lB1;
  PHASE(0, 0, 1, 1, NOPV, 1, NOPV)
  PHASE(0, 1, 0, 1, NOPV, 0, NOPV)
  PHASE(1, 1, 1, 0, NOPV, 0, NOPV)
  PHASE(1, 0, 0, 0, NOPV, 0, NOPV)

  // epilogue: C/D layout col=lane&15, row=(lane>>4)*4+reg
  // nontemporal: streaming 256MB output must not evict cached A/B panels
  const int ccol = bn + wn * 64 + (lane & 15);
  const int crow = bm + wm * 128 + ((lane >> 4) << 2);
#pragma unroll
  for (int ni = 0; ni < 4; ++ni) {
    const int o = ccol + ni * 16;
    const float sc = scale[o], bi = bias[o];
#pragma unroll
    for (int mi = 0; mi < 8; ++mi) {
#pragma unroll
      for (int rr = 0; rr < 4; ++rr) {
        __builtin_nontemporal_store(acc[mi][ni][rr] * sc + bi,
                                    &out[(size_t)(crow + mi * 16 + rr) * N + o]);
      }
    }
  }
}

// ---------------- m97 128x128 fallback ----------------

#define BM 128
#define BN 128
#define BK 64

__global__ __launch_bounds__(256) void gemm_bf16_kernel(
    const unsigned short* __restrict__ A, const unsigned short* __restrict__ B,
    const float* __restrict__ scale, const float* __restrict__ bias,
    float* __restrict__ out, int T, int K, int N) {
  __shared__ __align__(16) unsigned short lsA[BM * BK];
  __shared__ __align__(16) unsigned short lsB[BN * BK];

  const int nbn = N / BN;
  const int nwg = (T / BM) * nbn;
  const int q = nwg >> 3, r = nwg & 7;
  const int xcd = blockIdx.x & 7, off = blockIdx.x >> 3;
  const int swz = (xcd < r ? xcd * (q + 1) : r * (q + 1) + (xcd - r) * q) + off;
  const int bm = (swz / nbn) * BM;
  const int bn = (swz % nbn) * BN;

  const int tid = threadIdx.x;
  const int wave = tid >> 6, lane = tid & 63;
  const int wm = (wave >> 1) * 64, wn = (wave & 1) * 64;

  f32x4 acc[4][4] = {};

  const int srow = (wave << 3) + (lane >> 3);
  const int scolb = (lane & 7) * 16;
  const size_t Kb = (size_t)K * 2;
  const char* gA = (const char*)A + (size_t)bm * Kb + scolb;
  const char* gB = (const char*)B + (size_t)bn * Kb + scolb;
  char* laddrA = (char*)lsA + wave * 1024;
  char* laddrB = (char*)lsB + wave * 1024;

  for (int k0 = 0; k0 < K; k0 += BK) {
    const char* pa = gA + (size_t)k0 * 2;
    const char* pb = gB + (size_t)k0 * 2;
#pragma unroll
    for (int s = 0; s < 4; ++s) {
      int row = s * 32 + srow;
      gload_lds16(pa + (size_t)row * Kb, laddrA + s * 4096);
      gload_lds16(pb + (size_t)row * Kb, laddrB + s * 4096);
    }
    __syncthreads();

    const int arow2 = wm + (lane & 15);
    const int brow2 = wn + (lane & 15);
#pragma unroll
    for (int kk = 0; kk < BK; kk += 32) {
      const int kcol = kk + ((lane >> 4) << 3);
      bf16x8 af[4], bfr[4];
#pragma unroll
      for (int i = 0; i < 4; ++i)
        af[i] = *(const bf16x8*)(lsA + (size_t)(arow2 + i * 16) * BK + kcol);
#pragma unroll
      for (int i = 0; i < 4; ++i)
        bfr[i] = *(const bf16x8*)(lsB + (size_t)(brow2 + i * 16) * BK + kcol);
#pragma unroll
      for (int mi = 0; mi < 4; ++mi)
#pragma unroll
        for (int ni = 0; ni < 4; ++ni)
          acc[mi][ni] = __builtin_amdgcn_mfma_f32_16x16x32_bf16(
              af[mi], bfr[ni], acc[mi][ni], 0, 0, 0);
    }
    __syncthreads();
  }

  const int ccol = bn + wn + (lane & 15);
  const int crow0 = bm + wm + ((lane >> 4) << 2);
#pragma unroll
  for (int ni = 0; ni < 4; ++ni) {
    const int o = ccol + ni * 16;
    const float sc = scale[o], bi = bias[o];
#pragma unroll
    for (int mi = 0; mi < 4; ++mi) {
#pragma unroll
      for (int rr = 0; rr < 4; ++rr) {
        const int t2 = crow0 + mi * 16 + rr;
        out[(size_t)t2 * N + o] = acc[mi][ni][rr] * sc + bi;
      }
    }
  }
}

// ---------------- naive fallback ----------------

__global__ void naive_kernel(const float* __restrict__ X, const int* __restrict__ Wq,
                             const float* __restrict__ sc, const float* __restrict__ bs,
                             float* __restrict__ out, int T, int K, int N) {
  __shared__ float xt[16][16];
  __shared__ float wt[16][17];
  const int tx = threadIdx.x & 15, ty = threadIdx.x >> 4;
  const int t = blockIdx.y * 16 + ty, o = blockIdx.x * 16 + tx;
  float acc = 0.f;
  for (int k0 = 0; k0 < K; k0 += 16) {
    xt[ty][tx] = X[(size_t)t * K + k0 + tx];
    wt[ty][tx] = dec_e4m3(Wq[(size_t)(blockIdx.x * 16 + ty) * K + k0 + tx]);
    __syncthreads();
#pragma unroll
    for (int kk = 0; kk < 16; ++kk) acc += xt[ty][kk] * wt[tx][kk];
    __syncthreads();
  }
  out[(size_t)t * N + o] = acc * sc[o] + bs[o];
}

extern "C" void kernel_launch(void* const* d_in, const int* in_sizes, int n_in,
                              void* d_out, int out_size, void* d_ws, size_t ws_size,
                              hipStream_t stream) {
  const float* x  = (const float*)d_in[0];
  const int*   wq = (const int*)d_in[1];
  const float* sc = (const float*)d_in[2];
  const float* bi = (const float*)d_in[3];
  float* out = (float*)d_out;

  const int DOUT = in_sizes[2];
  const int DIN  = in_sizes[1] / DOUT;
  const int T    = in_sizes[0] / DIN;

  const size_t need = ((size_t)T * DIN + (size_t)DOUT * DIN) * 2;
  const bool ok256 = (T % 256 == 0) && (DOUT % 256 == 0) && (DIN % 256 == 0);
  const bool ok128 = (T % BM == 0) && (DOUT % BN == 0) && (DIN % BK == 0);

  if (ws_size >= need && (ok256 || ok128)) {
    unsigned short* xb = (unsigned short*)d_ws;
    unsigned short* wb = xb + (size_t)T * DIN;
    const int nx8 = (int)((size_t)T * DIN / 8);
    const int nw8 = (int)((size_t)DOUT * DIN / 8);
    cvt_x_kernel<<<(nx8 + 255) / 256, 256, 0, stream>>>(x, xb, nx8);
    dec_w_kernel<<<(nw8 + 255) / 256, 256, 0, stream>>>(wq, wb, nw8);
    if (ok256) {
      dim3 grid((T >> 8) * (DOUT >> 8));
      gemm256_kernel<<<grid, 512, 131072, stream>>>(xb, wb, sc, bi, out, T, DIN, DOUT);
    } else {
      dim3 grid((T / BM) * (DOUT / BN));
      gemm_bf16_kernel<<<grid, 256, 0, stream>>>(xb, wb, sc, bi, out, T, DIN, DOUT);
    }
  } else {
    dim3 g(DOUT / 16, T / 16);
    naive_kernel<<<g, 256, 0, stream>>>(x, wq, sc, bi, out, T, DIN, DOUT);
  }
}

// Round 7
// 515.184 us; speedup vs baseline: 1.4148x; 1.0040x over previous
//
#include <hip/hip_runtime.h>

using short8 = __attribute__((ext_vector_type(8))) short;
using bf16x8 = __attribute__((ext_vector_type(8))) __bf16;
using f32x4  = __attribute__((ext_vector_type(4))) float;

__device__ __forceinline__ void gload_lds16(const void* g, void* l) {
  __builtin_amdgcn_global_load_lds(
      (const __attribute__((address_space(1))) void*)g,
      (__attribute__((address_space(3))) void*)l, 16, 0, 0);
}

// ---------------- prepass: decode/convert ----------------

__device__ __forceinline__ float dec_e4m3(int b) {
  int e = (b >> 3) & 15;
  int m = b & 7;
  if (e == 15 && m == 7) m = 6;  // NaN pattern -> 448 per reference
  float v;
  if (e) v = (1.0f + (float)m * 0.125f) * __uint_as_float((unsigned)(e + 120) << 23);
  else   v = (float)m * 0.001953125f;  // m * 2^-9
  return (b & 0x80) ? -v : v;
}

__global__ void dec_w_kernel(const int* __restrict__ wq,
                             unsigned short* __restrict__ wb, int n8) {
  int i = blockIdx.x * blockDim.x + threadIdx.x;
  if (i >= n8) return;
  const int4* p = (const int4*)wq + (size_t)i * 2;
  int4 a = p[0], b4 = p[1];
  int bv[8] = {a.x, a.y, a.z, a.w, b4.x, b4.y, b4.z, b4.w};
  short8 r;
#pragma unroll
  for (int j = 0; j < 8; ++j) {
    float f = dec_e4m3(bv[j]);
    r[j] = (short)(__float_as_uint(f) >> 16);  // exact (<=3 mantissa bits)
  }
  *(short8*)(wb + (size_t)i * 8) = r;
}

__global__ void cvt_x_kernel(const float* __restrict__ x,
                             unsigned short* __restrict__ xb, int n8) {
  int i = blockIdx.x * blockDim.x + threadIdx.x;
  if (i >= n8) return;
  const float4* p = (const float4*)x + (size_t)i * 2;
  float4 a = p[0], b4 = p[1];
  float v[8] = {a.x, a.y, a.z, a.w, b4.x, b4.y, b4.z, b4.w};
  short8 r;
#pragma unroll
  for (int j = 0; j < 8; ++j) {
    unsigned u = __float_as_uint(v[j]);
    u += 0x7FFFu + ((u >> 16) & 1u);  // RNE
    r[j] = (short)(u >> 16);
  }
  *(short8*)(xb + (size_t)i * 8) = r;
}

// ---------------- 256x256 8-phase GEMM, persistent 4-tile chains ----------
// C[t,o] = scale[o] * sum_k A[t,k]*B[o,k] + bias[o]
// A: [T][K] bf16, B: [N][K] bf16 (row-major, B^T GEMM). 512 thr = 8 waves
// (2M x 4N), per-wave C 128x64. LDS 128KB double-buffered. XOR swizzle via
// pre-swizzled global source (0 bank conflicts, R2-verified).
// R7: grid = nwg/4; each block chains 4 bm-consecutive tiles at fixed bn.
// Chain transition reuses the pipeline: next tile's k0 staged in the tail's
// last 4 phases (buf0 free), epilogue NT-stores overlap k1 stages, one
// VM6+barrier replaces the cold prologue. scale/bias hoisted (bn-invariant).

#define NOPV ((void)0)
#define VM6 asm volatile("s_waitcnt vmcnt(6)" ::: "memory")
#define VM0 asm volatile("s_waitcnt vmcnt(0)" ::: "memory")

#define STAGE_A(GP, LBUF, KT, J) do { \
    const char* _g = (GP) + (size_t)(KT) * 128u; \
    gload_lds16(_g + (size_t)((J) * 64) * Kb, (LBUF) + ((J) * 64) * 128 + tdA); \
    gload_lds16(_g + (size_t)(128 + (J) * 64) * Kb, (LBUF) + (128 + (J) * 64) * 128 + tdA); \
  } while (0)

#define STAGE_B(GP, LBUF, KT, J) do { \
    const char* _g = (GP) + (size_t)(KT) * 128u; \
    gload_lds16(_g + (size_t)((J) * 32) * Kb, (LBUF) + ((J) * 32) * 128 + tdB); \
    gload_lds16(_g + (size_t)(128 + (J) * 32) * Kb, (LBUF) + (128 + (J) * 32) * 128 + tdB); \
  } while (0)

#define PHASE(QM, QN, DOA, DOB, STAGE, LGK8, VM) { \
    if (DOA) { \
      _Pragma("unroll") \
      for (int mi = 0; mi < 4; ++mi) { \
        const char* _b = lA + (size_t)(arow + (QM) * 64 + mi * 16) * 128; \
        a[mi][0] = *(const bf16x8*)(_b + fo0); \
        a[mi][1] = *(const bf16x8*)(_b + fo1); \
      } \
    } \
    if (DOB) { \
      _Pragma("unroll") \
      for (int ni = 0; ni < 2; ++ni) { \
        const char* _b = lB + (size_t)(brow + ((QN) * 2 + ni) * 16) * 128; \
        b[(QN) * 2 + ni][0] = *(const bf16x8*)(_b + fo0); \
        b[(QN) * 2 + ni][1] = *(const bf16x8*)(_b + fo1); \
      } \
    } \
    STAGE; \
    if (LGK8) asm volatile("s_waitcnt lgkmcnt(8)" ::: "memory"); \
    __builtin_amdgcn_s_barrier(); \
    asm volatile("s_waitcnt lgkmcnt(0)" ::: "memory"); \
    __builtin_amdgcn_sched_barrier(0); \
    __builtin_amdgcn_s_setprio(1); \
    _Pragma("unroll") \
    for (int mi = 0; mi < 4; ++mi) \
      _Pragma("unroll") \
      for (int ni = 0; ni < 2; ++ni) \
        _Pragma("unroll") \
        for (int ks = 0; ks < 2; ++ks) \
          acc[(QM) * 4 + mi][(QN) * 2 + ni] = __builtin_amdgcn_mfma_f32_16x16x32_bf16( \
              a[mi][ks], b[(QN) * 2 + ni][ks], acc[(QM) * 4 + mi][(QN) * 2 + ni], 0, 0, 0); \
    __builtin_amdgcn_s_setprio(0); \
    VM; \
    __builtin_amdgcn_s_barrier(); \
  }

__global__ __launch_bounds__(512, 2) void gemm256_kernel(
    const unsigned short* __restrict__ A, const unsigned short* __restrict__ B,
    const float* __restrict__ scale, const float* __restrict__ bias,
    float* __restrict__ out, int T, int K, int N) {
  extern __shared__ char lds[];
  char* const lA0 = lds;
  char* const lB0 = lds + 32768;
  char* const lA1 = lds + 65536;
  char* const lB1 = lds + 98304;

  const int nbn = N >> 8;
  const int nbm = T >> 8;
  int bm, bn, CH;
  if (((nbm & 3) == 0) && ((nbn & 7) == 0) &&
      (int)gridDim.x == (nbm >> 2) * nbn) {
    // chained: XCD x owns bn columns [x*cpx, (x+1)*cpx); block walks 4 bm tiles
    const int xcd = blockIdx.x & 7, off = blockIdx.x >> 3;
    const int cpx = nbn >> 3;
    const int col = xcd * cpx + (off % cpx);
    const int ci  = off / cpx;
    bm = (ci * 4) << 8;
    bn = col << 8;
    CH = 4;
  } else {
    // bijective m204 fallback, 1 tile per block
    const int nwg = nbm * nbn;
    const int q = nwg >> 3, r = nwg & 7;
    const int xcd = blockIdx.x & 7, off = blockIdx.x >> 3;
    const int swz = (xcd < r ? xcd * (q + 1) : r * (q + 1) + (xcd - r) * q) + off;
    bm = (swz / nbn) << 8;
    bn = (swz % nbn) << 8;
    CH = 1;
  }

  const int tid = threadIdx.x;
  const int wave = tid >> 6, lane = tid & 63;
  const int wm = wave >> 2, wn = wave & 3;
  const int nt = K >> 6;           // K-tiles (BK=64); requires nt even >= 4
  const size_t Kb = (size_t)K * 2; // row stride bytes

  // staging addresses (pre-swizzled global source, linear LDS dest)
  const int trow = tid >> 3;
  const int gcol = ((tid & 7) * 16) ^ (((tid >> 3) & 7) << 4);
  const int bmap = ((tid & 256) ? 64 : 0) + ((tid >> 6) & 3) * 8 + ((tid >> 3) & 7);
  const char* gAb = (const char*)A + (size_t)(bm + trow) * Kb + gcol;
  const char* gBb = (const char*)B + (size_t)(bn + bmap) * Kb + gcol;
  const int tdA = tid * 16;
  const int tdB = bmap * 128 + (tid & 7) * 16;

  // ds_read fragment addressing (same XOR swizzle)
  const int g16 = lane >> 4, l8 = lane & 7;
  const int fo0 = ((g16 ^ l8) << 4);
  const int fo1 = fo0 ^ 64;
  const int arow = wm * 128 + (lane & 15);
  const int brow = wn * 64 + (lane & 15);

  // epilogue addressing + hoisted scale/bias (bn fixed for whole chain)
  const int ccol = bn + wn * 64 + (lane & 15);
  int crow = bm + wm * 128 + ((lane >> 4) << 2);
  float scv[4], biv[4];
#pragma unroll
  for (int ni = 0; ni < 4; ++ni) {
    scv[ni] = scale[ccol + ni * 16];
    biv[ni] = bias[ccol + ni * 16];
  }

  f32x4 acc[8][4] = {};
  bf16x8 a[4][2], b[4][2];
  const char *lA, *lB;

  for (int ch = 0; ch < CH; ++ch) {
    const bool more = (ch + 1 < CH);
    const char* gAn = gAb + (size_t)256 * Kb;  // next chain tile's A base

    if (ch == 0) {
      // cold prologue: tile0 {A0,B0,B1,A1}; tile1 {A0,B0,B1}; vmcnt(6)
      STAGE_A(gAb, lA0, 0, 0);
      STAGE_B(gBb, lB0, 0, 0);
      STAGE_B(gBb, lB0, 0, 1);
      STAGE_A(gAb, lA0, 0, 1);
      STAGE_A(gAb, lA1, 1, 0);
      STAGE_B(gBb, lB1, 1, 0);
      STAGE_B(gBb, lB1, 1, 1);
      VM6;
      __builtin_amdgcn_s_barrier();
    }

    int t = 0;
    for (; t + 3 < nt; t += 2) {
      lA = lA0; lB = lB0;
      PHASE(0, 0, 1, 1, STAGE_A(gAb, lA1, t + 1, 1), 1, NOPV)
      PHASE(0, 1, 0, 1, STAGE_A(gAb, lA0, t + 2, 0), 0, NOPV)
      PHASE(1, 1, 1, 0, STAGE_B(gBb, lB0, t + 2, 0), 0, NOPV)
      PHASE(1, 0, 0, 0, STAGE_B(gBb, lB0, t + 2, 1), 0, VM6)
      lA = lA1; lB = lB1;
      PHASE(0, 0, 1, 1, STAGE_A(gAb, lA0, t + 2, 1), 1, NOPV)
      PHASE(0, 1, 0, 1, STAGE_A(gAb, lA1, t + 3, 0), 0, NOPV)
      PHASE(1, 1, 1, 0, STAGE_B(gBb, lB1, t + 3, 0), 0, NOPV)
      PHASE(1, 0, 0, 0, STAGE_B(gBb, lB1, t + 3, 1), 0, VM6)
    }
    // tail tile nt-2 (buf0); VM0 ensures buf1 complete before phases 5-8
    lA = lA0; lB = lB0;
    PHASE(0, 0, 1, 1, STAGE_A(gAb, lA1, t + 1, 1), 1, NOPV)
    PHASE(0, 1, 0, 1, NOPV, 0, NOPV)
    PHASE(1, 1, 1, 0, NOPV, 0, NOPV)
    PHASE(1, 0, 0, 0, NOPV, 0, VM0)
    // tail tile nt-1 (buf1); stage next chain tile's k0 into free buf0
    lA = lA1; lB = lB1;
    PHASE(0, 0, 1, 1, { if (more) STAGE_A(gAn, lA0, 0, 0); }, 1, NOPV)
    PHASE(0, 1, 0, 1, { if (more) STAGE_B(gBb, lB0, 0, 0); }, 0, NOPV)
    PHASE(1, 1, 1, 0, { if (more) STAGE_B(gBb, lB0, 0, 1); }, 0, NOPV)
    PHASE(1, 0, 0, 0, { if (more) STAGE_A(gAn, lA0, 0, 1); }, 0, NOPV)

    // epilogue: C/D layout col=lane&15, row=(lane>>4)*4+reg; NT stores
#pragma unroll
    for (int ni = 0; ni < 4; ++ni) {
      const int o = ccol + ni * 16;
#pragma unroll
      for (int mi = 0; mi < 8; ++mi) {
#pragma unroll
        for (int rr = 0; rr < 4; ++rr) {
          __builtin_nontemporal_store(acc[mi][ni][rr] * scv[ni] + biv[ni],
                                      &out[(size_t)(crow + mi * 16 + rr) * N + o]);
        }
      }
    }

    if (more) {
      // zero accumulators for the next tile
#pragma unroll
      for (int mi = 0; mi < 8; ++mi)
#pragma unroll
        for (int ni = 0; ni < 4; ++ni)
          acc[mi][ni] = (f32x4){0.f, 0.f, 0.f, 0.f};
      // stage next tile's k1, restore steady-state invariant (6 outstanding)
      STAGE_A(gAn, lA1, 1, 0);
      STAGE_B(gBb, lB1, 1, 0);
      STAGE_B(gBb, lB1, 1, 1);
      VM6;
      __builtin_amdgcn_s_barrier();
      gAb = gAn;
      crow += 256;
    }
  }
}

// ---------------- m97 128x128 fallback ----------------

#define BM 128
#define BN 128
#define BK 64

__global__ __launch_bounds__(256) void gemm_bf16_kernel(
    const unsigned short* __restrict__ A, const unsigned short* __restrict__ B,
    const float* __restrict__ scale, const float* __restrict__ bias,
    float* __restrict__ out, int T, int K, int N) {
  __shared__ __align__(16) unsigned short lsA[BM * BK];
  __shared__ __align__(16) unsigned short lsB[BN * BK];

  const int nbn = N / BN;
  const int nwg = (T / BM) * nbn;
  const int q = nwg >> 3, r = nwg & 7;
  const int xcd = blockIdx.x & 7, off = blockIdx.x >> 3;
  const int swz = (xcd < r ? xcd * (q + 1) : r * (q + 1) + (xcd - r) * q) + off;
  const int bm = (swz / nbn) * BM;
  const int bn = (swz % nbn) * BN;

  const int tid = threadIdx.x;
  const int wave = tid >> 6, lane = tid & 63;
  const int wm = (wave >> 1) * 64, wn = (wave & 1) * 64;

  f32x4 acc[4][4] = {};

  const int srow = (wave << 3) + (lane >> 3);
  const int scolb = (lane & 7) * 16;
  const size_t Kb = (size_t)K * 2;
  const char* gA = (const char*)A + (size_t)bm * Kb + scolb;
  const char* gB = (const char*)B + (size_t)bn * Kb + scolb;
  char* laddrA = (char*)lsA + wave * 1024;
  char* laddrB = (char*)lsB + wave * 1024;

  for (int k0 = 0; k0 < K; k0 += BK) {
    const char* pa = gA + (size_t)k0 * 2;
    const char* pb = gB + (size_t)k0 * 2;
#pragma unroll
    for (int s = 0; s < 4; ++s) {
      int row = s * 32 + srow;
      gload_lds16(pa + (size_t)row * Kb, laddrA + s * 4096);
      gload_lds16(pb + (size_t)row * Kb, laddrB + s * 4096);
    }
    __syncthreads();

    const int arow2 = wm + (lane & 15);
    const int brow2 = wn + (lane & 15);
#pragma unroll
    for (int kk = 0; kk < BK; kk += 32) {
      const int kcol = kk + ((lane >> 4) << 3);
      bf16x8 af[4], bfr[4];
#pragma unroll
      for (int i = 0; i < 4; ++i)
        af[i] = *(const bf16x8*)(lsA + (size_t)(arow2 + i * 16) * BK + kcol);
#pragma unroll
      for (int i = 0; i < 4; ++i)
        bfr[i] = *(const bf16x8*)(lsB + (size_t)(brow2 + i * 16) * BK + kcol);
#pragma unroll
      for (int mi = 0; mi < 4; ++mi)
#pragma unroll
        for (int ni = 0; ni < 4; ++ni)
          acc[mi][ni] = __builtin_amdgcn_mfma_f32_16x16x32_bf16(
              af[mi], bfr[ni], acc[mi][ni], 0, 0, 0);
    }
    __syncthreads();
  }

  const int ccol = bn + wn + (lane & 15);
  const int crow0 = bm + wm + ((lane >> 4) << 2);
#pragma unroll
  for (int ni = 0; ni < 4; ++ni) {
    const int o = ccol + ni * 16;
    const float sc = scale[o], bi = bias[o];
#pragma unroll
    for (int mi = 0; mi < 4; ++mi) {
#pragma unroll
      for (int rr = 0; rr < 4; ++rr) {
        const int t2 = crow0 + mi * 16 + rr;
        out[(size_t)t2 * N + o] = acc[mi][ni][rr] * sc + bi;
      }
    }
  }
}

// ---------------- naive fallback ----------------

__global__ void naive_kernel(const float* __restrict__ X, const int* __restrict__ Wq,
                             const float* __restrict__ sc, const float* __restrict__ bs,
                             float* __restrict__ out, int T, int K, int N) {
  __shared__ float xt[16][16];
  __shared__ float wt[16][17];
  const int tx = threadIdx.x & 15, ty = threadIdx.x >> 4;
  const int t = blockIdx.y * 16 + ty, o = blockIdx.x * 16 + tx;
  float acc = 0.f;
  for (int k0 = 0; k0 < K; k0 += 16) {
    xt[ty][tx] = X[(size_t)t * K + k0 + tx];
    wt[ty][tx] = dec_e4m3(Wq[(size_t)(blockIdx.x * 16 + ty) * K + k0 + tx]);
    __syncthreads();
#pragma unroll
    for (int kk = 0; kk < 16; ++kk) acc += xt[ty][kk] * wt[tx][kk];
    __syncthreads();
  }
  out[(size_t)t * N + o] = acc * sc[o] + bs[o];
}

extern "C" void kernel_launch(void* const* d_in, const int* in_sizes, int n_in,
                              void* d_out, int out_size, void* d_ws, size_t ws_size,
                              hipStream_t stream) {
  const float* x  = (const float*)d_in[0];
  const int*   wq = (const int*)d_in[1];
  const float* sc = (const float*)d_in[2];
  const float* bi = (const float*)d_in[3];
  float* out = (float*)d_out;

  const int DOUT = in_sizes[2];
  const int DIN  = in_sizes[1] / DOUT;
  const int T    = in_sizes[0] / DIN;

  const size_t need = ((size_t)T * DIN + (size_t)DOUT * DIN) * 2;
  const bool ok256 = (T % 256 == 0) && (DOUT % 256 == 0) && (DIN % 256 == 0);
  const bool ok128 = (T % BM == 0) && (DOUT % BN == 0) && (DIN % BK == 0);

  if (ws_size >= need && (ok256 || ok128)) {
    unsigned short* xb = (unsigned short*)d_ws;
    unsigned short* wb = xb + (size_t)T * DIN;
    const int nx8 = (int)((size_t)T * DIN / 8);
    const int nw8 = (int)((size_t)DOUT * DIN / 8);
    cvt_x_kernel<<<(nx8 + 255) / 256, 256, 0, stream>>>(x, xb, nx8);
    dec_w_kernel<<<(nw8 + 255) / 256, 256, 0, stream>>>(wq, wb, nw8);
    if (ok256) {
      const int nbm = T >> 8, nbn = DOUT >> 8;
      const bool okchain = ((nbm & 3) == 0) && ((nbn & 7) == 0);
      const int grid = okchain ? (nbm >> 2) * nbn : nbm * nbn;
      gemm256_kernel<<<grid, 512, 131072, stream>>>(xb, wb, sc, bi, out, T, DIN, DOUT);
    } else {
      dim3 grid((T / BM) * (DOUT / BN));
      gemm_bf16_kernel<<<grid, 256, 0, stream>>>(xb, wb, sc, bi, out, T, DIN, DOUT);
    }
  } else {
    dim3 g(DOUT / 16, T / 16);
    naive_kernel<<<g, 256, 0, stream>>>(x, wq, sc, bi, out, T, DIN, DOUT);
  }
}